// Round 3
// baseline (643.447 us; speedup 1.0000x reference)
//
#include <hip/hip_runtime.h>
#include <math.h>

typedef unsigned short u16;
typedef short s8v __attribute__((ext_vector_type(8)));   // 8 bf16 = one MFMA A/B frag
typedef float f4v __attribute__((ext_vector_type(4)));   // MFMA C/D frag

__device__ inline float b2f(u16 u) {
    union { unsigned int i; float f; } v; v.i = ((unsigned int)u) << 16; return v.f;
}
__device__ inline u16 f2b(float f) {  // round-to-nearest-even
    unsigned int x = __float_as_uint(f);
    return (u16)((x + 0x7fffu + ((x >> 16) & 1u)) >> 16);
}
// raw-input scalar load honoring runtime dtype flag (1 = f32, 0 = bf16)
__device__ inline float ldf(const void* p, size_t i, int f32) {
    return f32 ? ((const float*)p)[i] : b2f(((const u16*)p)[i]);
}
// raw-input 8-element load -> bf16 frag
__device__ inline s8v load8(const void* p, size_t idx, int f32) {
    if (f32) {
        const float* f = (const float*)p + idx;
        float4 a = *(const float4*)(f);
        float4 b = *(const float4*)(f + 4);
        s8v r;
        r[0] = (short)f2b(a.x); r[1] = (short)f2b(a.y);
        r[2] = (short)f2b(a.z); r[3] = (short)f2b(a.w);
        r[4] = (short)f2b(b.x); r[5] = (short)f2b(b.y);
        r[6] = (short)f2b(b.z); r[7] = (short)f2b(b.w);
        return r;
    }
    return *(const s8v*)((const u16*)p + idx);
}

// ---------------------------------------------------------------------------
// Runtime dtype detection. hg_1hop entries are uniform[0, 2/4096] ~ [0,4.9e-4].
// Interpreted as bf16, genuine bf16 data is all <= 1e-3; f32 data read as u16
// pairs yields ~9% wild values (random exponent from mantissa bits).
// flag: 0 = inputs bf16, 1 = inputs f32.
// ---------------------------------------------------------------------------
__global__ void detect_kernel(const u16* __restrict__ hg, int* __restrict__ flag) {
    int lane = threadIdx.x;  // 64 threads, 1 block
    bool ok = true;
    for (int i = 0; i < 32; ++i) {
        float v = b2f(hg[lane * 32 + i]);
        ok = ok && (fabsf(v) <= 1e-3f);   // NaN compares false
    }
    unsigned long long m = __ballot(ok);
    if (lane == 0) *flag = (m == ~0ull) ? 0 : 1;
}

// ---------------------------------------------------------------------------
// Big propagation GEMM: part[ky] = G[128-row tile] @ Z (Zt internal bf16
// [128][4096]). BM=128, BN=128 (full N), BK=64, split-K = gridDim.y.
// block 512 (8 waves: 2 m-waves x 4 n-waves, each 64m x 32n).
// ---------------------------------------------------------------------------
__global__ __launch_bounds__(512) void big_gemm(const void* __restrict__ G,
                                                const u16* __restrict__ Zt,
                                                float* __restrict__ part,
                                                int kChunkLen,
                                                const int* __restrict__ dflag) {
    __shared__ u16 At[128 * 72];
    __shared__ u16 Bt[128 * 72];
    const int f32 = *dflag;
    const int tid = threadIdx.x;
    const int rowBase = blockIdx.x * 128;
    const int kChunk = blockIdx.y * kChunkLen;
    const int w = tid >> 6, lane = tid & 63;
    const int wm = w & 1, wn = w >> 1;
    const int l15 = lane & 15, quad = lane >> 4;
    const int nIter = kChunkLen >> 6;

    const int r0 = tid >> 3, kb0 = tid & 7;
    const int r1 = 64 + (tid >> 3), kb1 = tid & 7;

    f4v acc[4][2] = {};

    for (int it = 0; it < nIter; ++it) {
        const int kBase = kChunk + it * 64;
        s8v ga0 = load8(G, (size_t)(rowBase + r0) * 4096 + kBase + kb0 * 8, f32);
        s8v gb0 = *(const s8v*)(Zt + (size_t)r0 * 4096 + kBase + kb0 * 8);
        s8v ga1 = load8(G, (size_t)(rowBase + r1) * 4096 + kBase + kb1 * 8, f32);
        s8v gb1 = *(const s8v*)(Zt + (size_t)r1 * 4096 + kBase + kb1 * 8);
        __syncthreads();  // prior iter's ds_reads done before overwrite
        *(s8v*)(At + r0 * 72 + kb0 * 8) = ga0;
        *(s8v*)(Bt + r0 * 72 + kb0 * 8) = gb0;
        *(s8v*)(At + r1 * 72 + kb1 * 8) = ga1;
        *(s8v*)(Bt + r1 * 72 + kb1 * 8) = gb1;
        __syncthreads();
#pragma unroll
        for (int ks = 0; ks < 2; ++ks) {
            s8v a[4], b[2];
            const int kq = ks * 4 + quad;
#pragma unroll
            for (int mi = 0; mi < 4; ++mi)
                a[mi] = *(const s8v*)(At + (wm * 64 + mi * 16 + l15) * 72 + kq * 8);
#pragma unroll
            for (int ni = 0; ni < 2; ++ni)
                b[ni] = *(const s8v*)(Bt + (wn * 32 + ni * 16 + l15) * 72 + kq * 8);
#pragma unroll
            for (int mi = 0; mi < 4; ++mi)
#pragma unroll
                for (int ni = 0; ni < 2; ++ni)
                    acc[mi][ni] = __builtin_amdgcn_mfma_f32_16x16x32_bf16(
                        a[mi], b[ni], acc[mi][ni], 0, 0, 0);
        }
    }
    float* pbase = part + (size_t)blockIdx.y * 4096 * 128;
#pragma unroll
    for (int mi = 0; mi < 4; ++mi)
#pragma unroll
        for (int ni = 0; ni < 2; ++ni) {
            int row = rowBase + wm * 64 + mi * 16 + quad * 4;
            int col = wn * 32 + ni * 16 + l15;
#pragma unroll
            for (int r = 0; r < 4; ++r)
                pbase[(size_t)(row + r) * 128 + col] = acc[mi][ni][r];
        }
}

// ---------------------------------------------------------------------------
// Split-K reduce + fused epilogue. mode: 0=relu(t), 1=relu(t+res),
// 2=relu(t+res)*beta, 3=t. out internal bf16.
// ---------------------------------------------------------------------------
__global__ __launch_bounds__(256) void reduce_epi(const float* __restrict__ part,
                                                  const u16* __restrict__ res,
                                                  const void* __restrict__ betap,
                                                  u16* __restrict__ out, int mode,
                                                  int S, const int* __restrict__ dflag) {
    int i = (blockIdx.x * 256 + threadIdx.x) * 4;
    f4v t = {};
    for (int s = 0; s < S; ++s)
        t += *(const f4v*)(part + (size_t)s * 524288 + i);
    float bscale = (mode == 2) ? ldf(betap, 0, *dflag) : 1.0f;
    u16 o[4];
#pragma unroll
    for (int j = 0; j < 4; ++j) {
        float v = t[j];
        if (mode == 1 || mode == 2) v += b2f(res[i + j]);
        if (mode <= 2) v = fmaxf(v, 0.0f);
        if (mode == 2) v *= bscale;
        o[j] = f2b(v);
    }
    *(ushort4*)(out + i) = make_ushort4(o[0], o[1], o[2], o[3]);
}

// ---------------------------------------------------------------------------
// Feature GEMM: out = A[M,128] @ B[128,Nc] + bias.
// wLayout 0: W[K=128][Nc] (x@W)   -> transpose into LDS
// wLayout 1: W[Nc][K=128] (x@W.T) -> direct copy
// outMode 0: [M][NcTotal]; outMode 1: transposed Zt[Nc][M] (internal bf16).
// aRaw: A is a raw input (dtype per flag); outRaw: out is d_out (dtype per
// flag, with optional bf16 mirror). outOfs: element offset into out.
// ---------------------------------------------------------------------------
__global__ __launch_bounds__(256) void feat_gemm(const void* __restrict__ A,
                                                 const void* __restrict__ W,
                                                 const void* __restrict__ bias,
                                                 void* __restrict__ out,
                                                 u16* __restrict__ mirror,
                                                 size_t outOfs,
                                                 int M, int NcTotal, int wLayout,
                                                 int outMode, int aRaw, int outRaw,
                                                 const int* __restrict__ dflag) {
    __shared__ char smem[52224];
    u16* Wt = (u16*)smem;              // [128][136]
    u16* At = (u16*)(smem + 34816);    // [64][136]
    u16* Tt = (u16*)smem;              // [128][72], aliases Wt after MFMA+sync
    const int f32 = *dflag;
    const int aF32 = aRaw & f32;
    const int tid = threadIdx.x;
    const int rowBase = blockIdx.x * 64;
    const int colBase = blockIdx.y * 128;

    if (wLayout == 1) {
#pragma unroll
        for (int i = 0; i < 8; ++i) {
            int c = i * 256 + tid;          // 2048 chunks of 8
            int n = c >> 4, kb = c & 15;
            s8v v = load8(W, (size_t)(colBase + n) * 128 + kb * 8, f32);
            *(s8v*)(Wt + n * 136 + kb * 8) = v;
        }
    } else {
#pragma unroll
        for (int i = 0; i < 64; ++i) {
            int idx = i * 256 + tid;        // 16384 elems
            int k = idx >> 7, n = idx & 127;
            Wt[n * 136 + k] = f2b(ldf(W, (size_t)k * NcTotal + colBase + n, f32));
        }
    }
#pragma unroll
    for (int i = 0; i < 4; ++i) {
        int c = i * 256 + tid;              // 1024 chunks
        int r = c >> 4, kb = c & 15;
        s8v v = load8(A, (size_t)(rowBase + r) * 128 + kb * 8, aF32);
        *(s8v*)(At + r * 136 + kb * 8) = v;
    }
    __syncthreads();

    const int w = tid >> 6, lane = tid & 63, l15 = lane & 15, quad = lane >> 4;
    f4v acc[8] = {};
#pragma unroll
    for (int ks = 0; ks < 4; ++ks) {
        int k = ks * 32 + quad * 8;
        s8v a = *(const s8v*)(At + (w * 16 + l15) * 136 + k);
#pragma unroll
        for (int ni = 0; ni < 8; ++ni) {
            s8v b = *(const s8v*)(Wt + (ni * 16 + l15) * 136 + k);
            acc[ni] = __builtin_amdgcn_mfma_f32_16x16x32_bf16(a, b, acc[ni], 0, 0, 0);
        }
    }

    if (outMode == 0) {
#pragma unroll
        for (int ni = 0; ni < 8; ++ni) {
            int n = colBase + ni * 16 + l15;
            float bv = ldf(bias, n, f32);
#pragma unroll
            for (int r = 0; r < 4; ++r) {
                int row = rowBase + w * 16 + quad * 4 + r;
                size_t idx = (size_t)row * NcTotal + n;
                float v = acc[ni][r] + bv;
                u16 vb = f2b(v);
                if (outRaw && f32) ((float*)out)[outOfs + idx] = v;
                else               ((u16*)out)[outOfs + idx] = vb;
                if (mirror) mirror[idx] = vb;
            }
        }
    } else {
        __syncthreads();  // all waves done reading Wt before aliasing as Tt
#pragma unroll
        for (int ni = 0; ni < 8; ++ni) {
            int n = ni * 16 + l15;
            float bv = ldf(bias, colBase + n, f32);
#pragma unroll
            for (int r = 0; r < 4; ++r)
                Tt[n * 72 + (w * 16 + quad * 4 + r)] = f2b(acc[ni][r] + bv);
        }
        __syncthreads();
#pragma unroll
        for (int i = 0; i < 4; ++i) {
            int c = i * 256 + tid;          // 1024 chunks: [128 h][8 node-chunks]
            int h = c >> 3, nb = c & 7;
            s8v v = *(const s8v*)(Tt + h * 72 + nb * 8);
            *(s8v*)((u16*)out + (size_t)(colBase + h) * M + rowBase + nb * 8) = v;
        }
    }
}

// ---------------------------------------------------------------------------
// mixup: xin[0][n] = l*Ph1[n] + (1-l)*Ph1[perm[n]]; xin[1][n] same with Ph3.
// (hg[perm][:,perm] @ Z[perm] == (hg @ Z)[perm].)
// ---------------------------------------------------------------------------
__global__ __launch_bounds__(256) void mix_kernel(const u16* __restrict__ Ph1,
                                                  const u16* __restrict__ Ph3,
                                                  const int* __restrict__ perm,
                                                  const void* __restrict__ lamp,
                                                  u16* __restrict__ xin,
                                                  const int* __restrict__ dflag) {
    int i = blockIdx.x * 256 + threadIdx.x;    // 524288
    int n = i >> 7, h = i & 127;
    float l = ldf(lamp, 0, *dflag);
    int pn = perm[n];
    float a = l * b2f(Ph1[i]) + (1.0f - l) * b2f(Ph1[(size_t)pn * 128 + h]);
    float b = l * b2f(Ph3[i]) + (1.0f - l) * b2f(Ph3[(size_t)pn * 128 + h]);
    xin[i] = f2b(a);
    xin[524288 + i] = f2b(b);
}

// ---------------------------------------------------------------------------
// L=2 self-attention + mean over L (Wo applied afterwards by feat_gemm;
// mean commutes with the projection). One wave per node.
// ---------------------------------------------------------------------------
__global__ __launch_bounds__(256) void attn_kernel(const u16* __restrict__ qkv,
                                                   u16* __restrict__ obar, int nh) {
    int wid = threadIdx.x >> 6, lane = threadIdx.x & 63;
    int n = blockIdx.x * 4 + wid;
    const u16* r0 = qkv + (size_t)n * 384;
    const u16* r1 = qkv + (size_t)(4096 + n) * 384;
    int hd = 128 / nh;
    float scale = 1.0f / sqrtf((float)hd);
    float ov[2];
#pragma unroll
    for (int e = 0; e < 2; ++e) {
        int h = e * 64 + lane;
        float q0 = b2f(r0[h]),       q1 = b2f(r1[h]);
        float k0 = b2f(r0[128 + h]), k1 = b2f(r1[128 + h]);
        float v0 = b2f(r0[256 + h]), v1 = b2f(r1[256 + h]);
        float s00 = q0 * k0, s01 = q0 * k1, s10 = q1 * k0, s11 = q1 * k1;
        for (int off = hd >> 1; off; off >>= 1) {
            s00 += __shfl_xor(s00, off);
            s01 += __shfl_xor(s01, off);
            s10 += __shfl_xor(s10, off);
            s11 += __shfl_xor(s11, off);
        }
        s00 *= scale; s01 *= scale; s10 *= scale; s11 *= scale;
        float m0 = fmaxf(s00, s01), m1 = fmaxf(s10, s11);
        float e00 = expf(s00 - m0), e01 = expf(s01 - m0);
        float e10 = expf(s10 - m1), e11 = expf(s11 - m1);
        float a00 = e00 / (e00 + e01), a01 = e01 / (e00 + e01);
        float a10 = e10 / (e10 + e11), a11 = e11 / (e10 + e11);
        float o0 = a00 * v0 + a01 * v1;
        float o1 = a10 * v0 + a11 * v1;
        ov[e] = 0.5f * (o0 + o1);
    }
    obar[(size_t)n * 128 + lane] = f2b(ov[0]);
    obar[(size_t)n * 128 + 64 + lane] = f2b(ov[1]);
}

// ---------------------------------------------------------------------------
// Edge classifier: out[e] = concat(h3[i0],h3[i1]) @ Wc + bc.
// h3 comes from the internal bf16 mirror; out honors the dtype flag.
// ---------------------------------------------------------------------------
__global__ __launch_bounds__(256) void edge_kernel(const u16* __restrict__ h3,
                                                   const int* __restrict__ eidx,
                                                   const void* __restrict__ Wc,
                                                   const void* __restrict__ bc,
                                                   void* __restrict__ out,
                                                   const int* __restrict__ dflag) {
    __shared__ float w0[256], w1[256];
    const int f32 = *dflag;
    int t = threadIdx.x;
    w0[t] = ldf(Wc, (size_t)t * 2, f32);
    w1[t] = ldf(Wc, (size_t)t * 2 + 1, f32);
    __syncthreads();
    int e = blockIdx.x * 256 + t;
    float a0 = ldf(bc, 0, f32), a1 = ldf(bc, 1, f32);
#pragma unroll
    for (int p = 0; p < 2; ++p) {
        int node = eidx[p * 131072 + e];
        const s8v* row = (const s8v*)(h3 + (size_t)node * 128);
#pragma unroll
        for (int cch = 0; cch < 16; ++cch) {
            s8v d = row[cch];
#pragma unroll
            for (int j = 0; j < 8; ++j) {
                float f = b2f((u16)d[j]);
                int k = p * 128 + cch * 8 + j;
                a0 += f * w0[k];
                a1 += f * w1[k];
            }
        }
    }
    if (f32) {
        ((float*)out)[(size_t)e * 2] = a0;
        ((float*)out)[(size_t)e * 2 + 1] = a1;
    } else {
        ((u16*)out)[(size_t)e * 2] = f2b(a0);
        ((u16*)out)[(size_t)e * 2 + 1] = f2b(a1);
    }
}

// ---------------------------------------------------------------------------
extern "C" void kernel_launch(void* const* d_in, const int* in_sizes, int n_in,
                              void* d_out, int out_size, void* d_ws, size_t ws_size,
                              hipStream_t stream) {
    const void* x    = d_in[0];
    const void* G1   = d_in[1];
    const void* G3   = d_in[2];
    const int* eidx = (const int*)d_in[3];
    const int* perm = (const int*)d_in[4];
    const void* lam  = d_in[5];
    const void* beta = d_in[6];
    const void* W1 = d_in[7],  *b1 = d_in[8];
    const void* W2 = d_in[9],  *b2 = d_in[10];
    const void* W3 = d_in[11], *b3 = d_in[12];
    const void* W1h = d_in[13], *b1h = d_in[14];
    const void* W3h = d_in[15], *b3h = d_in[16];
    const void* W2m = d_in[17], *b2m = d_in[18];
    const void* W3m = d_in[19], *b3m = d_in[20];
    const void* Wqkv_mix = d_in[21], *bqkv_mix = d_in[22];
    const void* Wo_mix   = d_in[23], *bo_mix   = d_in[24];
    const void* Wqkv_fus = d_in[25], *bqkv_fus = d_in[26];
    const void* Wo_fus   = d_in[27], *bo_fus   = d_in[28];
    const void* Wc = d_in[29], *bc = d_in[30];

    const size_t MB = 1ull << 20;
    char* base = (char*)d_ws;
    // Persistent bf16 [4096,128] buffers: 1 MB each, 9 MB total.
    u16* Zt    = (u16*)(base + 0 * MB);   // also reused as bf16 h3 mirror at end
    u16* h1    = (u16*)(base + 1 * MB);
    u16* h2    = (u16*)(base + 2 * MB);
    u16* h3c1  = (u16*)(base + 3 * MB);
    u16* h1mix = (u16*)(base + 4 * MB);
    u16* h2mix = (u16*)(base + 5 * MB);
    u16* h3c2  = (u16*)(base + 6 * MB);
    u16* Ph1   = (u16*)(base + 7 * MB);
    u16* Ph3   = (u16*)(base + 8 * MB);
    int* dflag = (int*)(base + 9 * MB);
    char* pool = base + 9 * MB + 65536;
    size_t poolBytes = (ws_size > 9 * MB + 65536) ? ws_size - 9 * MB - 65536 : 0;
    int S = (poolBytes >= 16 * MB) ? 8 : (poolBytes >= 8 * MB) ? 4
          : (poolBytes >= 4 * MB) ? 2 : 1;
    int kLen = 4096 / S;
    float* part = (float*)pool;
    u16* xin  = (u16*)pool;            // [2,4096,128] = 2 MB
    u16* qkv  = (u16*)(pool + 2 * MB); // [8192,384]   = 6 MB
    u16* obar = (u16*)pool;            // [4096,128]   = 1 MB (xin dead by then)

    auto feat = [&](const void* A, const void* W, const void* b, void* o,
                    u16* mir, size_t ofs, int M, int Nc, int wl, int om,
                    int aRaw, int oRaw) {
        feat_gemm<<<dim3(M / 64, Nc / 128), 256, 0, stream>>>(
            A, W, b, o, mir, ofs, M, Nc, wl, om, aRaw, oRaw, dflag);
    };
    auto big = [&](const void* Gm) {
        big_gemm<<<dim3(32, S), 512, 0, stream>>>(Gm, Zt, part, kLen, dflag);
    };
    auto epi = [&](const u16* res, u16* o, int mode) {
        reduce_epi<<<512, 256, 0, stream>>>(part, res, beta, o, mode, S, dflag);
    };

    detect_kernel<<<1, 64, 0, stream>>>((const u16*)G1, dflag);

    // h1 = relu(G1 @ (x W1 + b1))
    feat(x, W1, b1, Zt, nullptr, 0, 4096, 128, 0, 1, 1, 0);  big(G1);  epi(nullptr, h1, 0);
    // h2 = relu(G1 @ (h1 W2 + b2) + h1)
    feat(h1, W2, b2, Zt, nullptr, 0, 4096, 128, 0, 1, 0, 0); big(G1);  epi(h1, h2, 1);
    // Ph1 = G1 @ (h1 W1h + b1h);  Ph3 = G3 @ (h1 W3h + b3h)
    feat(h1, W1h, b1h, Zt, nullptr, 0, 4096, 128, 0, 1, 0, 0); big(G1); epi(nullptr, Ph1, 3);
    feat(h1, W3h, b3h, Zt, nullptr, 0, 4096, 128, 0, 1, 0, 0); big(G3); epi(nullptr, Ph3, 3);
    // h3_c1 = relu(G1 @ (h2 W3 + b3) + h2)
    feat(h2, W3, b3, Zt, nullptr, 0, 4096, 128, 0, 1, 0, 0); big(G1);  epi(h2, h3c1, 1);
    // mixup + MHA(nh=2) + proj (mean over L folded into single proj of mean-o)
    mix_kernel<<<2048, 256, 0, stream>>>(Ph1, Ph3, perm, lam, xin, dflag);
    feat(xin, Wqkv_mix, bqkv_mix, qkv, nullptr, 0, 8192, 384, 1, 0, 0, 0);
    attn_kernel<<<1024, 256, 0, stream>>>(qkv, obar, 2);
    feat(obar, Wo_mix, bo_mix, h1mix, nullptr, 0, 4096, 128, 1, 0, 0, 0);
    // h2_mix, h3_c2
    feat(h1mix, W2m, b2m, Zt, nullptr, 0, 4096, 128, 0, 1, 0, 0); big(G1); epi(h1mix, h2mix, 1);
    feat(h2mix, W3m, b3m, Zt, nullptr, 0, 4096, 128, 0, 1, 0, 0); big(G1); epi(h2mix, h3c2, 2);
    // fusion MHA(nh=4) over [h3_c1, h3_c2]
    feat(h3c1, Wqkv_fus, bqkv_fus, qkv, nullptr, 0, 4096, 384, 1, 0, 0, 0);
    feat(h3c2, Wqkv_fus, bqkv_fus, qkv + (size_t)4096 * 384, nullptr, 0, 4096, 384, 1, 0, 0, 0);
    attn_kernel<<<1024, 256, 0, stream>>>(qkv, obar, 4);
    // h3 -> d_out (dtype per flag) at element offset 2*E; bf16 mirror in Zt
    feat(obar, Wo_fus, bo_fus, d_out, Zt, (size_t)131072 * 2, 4096, 128, 1, 0, 0, 1);
    // edge classifier -> d_out[0 .. 2E)
    edge_kernel<<<512, 256, 0, stream>>>(Zt, eidx, Wc, bc, d_out, dflag);
}